// Round 5
// baseline (75.843 us; speedup 1.0000x reference)
//
#include <hip/hip_runtime.h>

// R5: R4 + enforced software pipeline.
//   GEMM1 K-loop fully unrolled into 13 segments:
//     [issue A(t+2), B(t+2) loads] -> sched_barrier(0) -> [compute(t)]
//   Distance-2 register prefetch for both A and B; sched_barrier prevents the
//   scheduler from sinking loads to their uses (R4's failure: VGPR=76 proved
//   the dbuf was deallocated and every load serialized at ~710cy).
//   Still barrier-free (__syncthreads-free): per-wave rows only.

typedef __attribute__((ext_vector_type(8))) short bf16x8;
typedef __attribute__((ext_vector_type(4))) float f32x4;

#define KP1 832     // GEMM1 K padded (784 -> 13*64)
#define NP  112     // hidden N padded (100 -> 7*16)
#define K2P 128     // GEMM2/3 K padded (100 -> 128)
#define BM  64
#define NT  256

#define W2T_OFF (NP * KP1)              // 93184
#define W3T_OFF (W2T_OFF + NP * K2P)    // 107520
#define WS_USHORTS (W3T_OFF + 16 * K2P) // 109568

__device__ __forceinline__ unsigned short f2bf(float f) {
    unsigned int u = __float_as_uint(f);
    u += 0x7FFFu + ((u >> 16) & 1u);    // RNE
    return (unsigned short)(u >> 16);
}

__device__ __forceinline__ unsigned int pkbf(float a, float b) {
    unsigned int r;
    asm("v_cvt_pk_bf16_f32 %0, %1, %2" : "=v"(r) : "v"(a), "v"(b));
    return r;
}

__device__ __forceinline__ bf16x8 cvt8(float4 a, float4 b) {
    union { unsigned int w[4]; bf16x8 v; } u;
    u.w[0] = pkbf(a.x, a.y);
    u.w[1] = pkbf(a.z, a.w);
    u.w[2] = pkbf(b.x, b.y);
    u.w[3] = pkbf(b.z, b.w);
    return u.v;
}

// ---------------- Kernel A: all weights -> bf16, transposed, padded
__global__ void build_weights(const float* __restrict__ w_conv,
                              const float* __restrict__ W1,
                              const float* __restrict__ W2,
                              const float* __restrict__ W3,
                              unsigned short* __restrict__ ws) {
    const int idx = blockIdx.x * 256 + threadIdx.x;
    if (idx >= WS_USHORTS) return;
    float v = 0.f;
    if (idx < W2T_OFF) {                       // weff_t[col][p]
        const int col = idx / KP1, p = idx % KP1;
        if (col < 100 && p < 784) {
            const int y = p / 28, xx = p % 28;
#pragma unroll
            for (int ky = 0; ky < 3; ++ky) {
                const int py = y - ky;
                if (py < 0 || py >= 26) continue;
#pragma unroll
                for (int kx = 0; kx < 3; ++kx) {
                    const int px = xx - kx;
                    if (px < 0 || px >= 26) continue;
                    v += w_conv[ky * 3 + kx] * W1[(py * 26 + px) * 100 + col];
                }
            }
        }
    } else if (idx < W3T_OFF) {                // w2t[col][k] = W2[k][col]
        const int r = idx - W2T_OFF;
        const int col = r / K2P, k = r % K2P;
        if (col < 100 && k < 100) v = W2[k * 100 + col];
    } else {                                   // w3t[col][k] = W3[k][col]
        const int r = idx - W3T_OFF;
        const int col = r / K2P, k = r % K2P;
        if (col < 10 && k < 100) v = W3[k * 10 + col];
    }
    ws[idx] = f2bf(v);
}

// ---------------- Kernel B: fused, barrier-free, pipeline-enforced
__global__ __launch_bounds__(NT, 2)
void fused(const float* __restrict__ x,
           const unsigned short* __restrict__ wst,
           const float* __restrict__ b1,
           const float* __restrict__ b2,
           const float* __restrict__ b3,
           float* __restrict__ out) {
    __shared__ unsigned short h1[BM][136];
    __shared__ unsigned short h2[BM][136];

    const int tid  = threadIdx.x;
    const int lane = tid & 63;
    const int wv   = tid >> 6;       // wave owns rows wv*16 .. wv*16+15
    const int l15  = lane & 15;
    const int lk   = lane >> 4;      // 0..3
    const int b0   = blockIdx.x * BM;
    const int wr   = wv * 16;

    const unsigned short* weff = wst;
    const unsigned short* w2t  = wst + W2T_OFF;
    const unsigned short* w3t  = wst + W3T_OFF;

    // zero k-pad columns (100..135) of this wave's rows, both buffers
    for (int f = lane; f < 16 * 18; f += 64) {
        const int r = wr + f / 18, c = 100 + (f % 18) * 2;
        *reinterpret_cast<unsigned int*>(&h1[r][c]) = 0u;
        *reinterpret_cast<unsigned int*>(&h2[r][c]) = 0u;
    }

    const float* xr = x + (size_t)(b0 + wr + l15) * 784;

    f32x4 acc[7];
#pragma unroll
    for (int n = 0; n < 7; ++n) acc[n] = (f32x4){0.f, 0.f, 0.f, 0.f};

    float4 Ab[3][2][2];      // [buf][ks][half]
    bf16x8 Bb[3][2][7];      // [buf][ks][n]

    auto loadA = [&](int kt, float4 (&dst)[2][2]) {
#pragma unroll
        for (int ks = 0; ks < 2; ++ks)
#pragma unroll
            for (int h = 0; h < 2; ++h) {
                const int k = kt * 64 + ks * 32 + lk * 8 + h * 4;
                dst[ks][h] = (k < 784)
                    ? *reinterpret_cast<const float4*>(xr + k)
                    : (float4){0.f, 0.f, 0.f, 0.f};
            }
    };
    auto loadB = [&](int kt, bf16x8 (&dst)[2][7]) {
#pragma unroll
        for (int ks = 0; ks < 2; ++ks) {
            const int kb = kt * 64 + ks * 32 + lk * 8;
#pragma unroll
            for (int n = 0; n < 7; ++n)
                dst[ks][n] = *reinterpret_cast<const bf16x8*>(
                    weff + (size_t)(n * 16 + l15) * KP1 + kb);
        }
    };
    auto compute = [&](float4 (&A)[2][2], bf16x8 (&B)[2][7]) {
#pragma unroll
        for (int ks = 0; ks < 2; ++ks) {
            const bf16x8 af = cvt8(A[ks][0], A[ks][1]);
#pragma unroll
            for (int n = 0; n < 7; ++n)
                acc[n] = __builtin_amdgcn_mfma_f32_16x16x32_bf16(af, B[ks][n], acc[n], 0, 0, 0);
        }
    };

    // ---- GEMM1: 13 segments, distance-2 prefetch, sched_barrier-fenced
    loadA(0, Ab[0]); loadB(0, Bb[0]);
    loadA(1, Ab[1]); loadB(1, Bb[1]);
    __builtin_amdgcn_sched_barrier(0);
#pragma unroll
    for (int t = 0; t < 13; ++t) {
        if (t + 2 < 13) {
            loadA(t + 2, Ab[(t + 2) % 3]);
            loadB(t + 2, Bb[(t + 2) % 3]);
        }
        __builtin_amdgcn_sched_barrier(0);   // loads must issue before compute(t)
        compute(Ab[t % 3], Bb[t % 3]);
        __builtin_amdgcn_sched_barrier(0);   // compute(t) done before next issues
    }

    // ---- h1 = relu(acc + b1) -> LDS (own rows only)
    float bias[7];
#pragma unroll
    for (int n = 0; n < 7; ++n) {
        const int c = n * 16 + l15;
        bias[n] = (c < 100) ? b1[c] : 0.f;
    }
#pragma unroll
    for (int n = 0; n < 7; ++n) {
        const int col = n * 16 + l15;
        if (col < 100)
#pragma unroll
            for (int q = 0; q < 4; ++q) {
                const float v = fmaxf(acc[n][q] + bias[n], 0.f);
                h1[wr + lk * 4 + q][col] = f2bf(v);
            }
    }
    __builtin_amdgcn_sched_barrier(0);   // ds_writes stay before GEMM2 ds_reads

    // ---- GEMM2: h2 = relu(h1 @ W2 + b2)
    f32x4 acc2[7];
#pragma unroll
    for (int n = 0; n < 7; ++n) acc2[n] = (f32x4){0.f, 0.f, 0.f, 0.f};
#pragma unroll
    for (int ks = 0; ks < 4; ++ks) {
        const int kb = ks * 32 + lk * 8;
        const bf16x8 af = *reinterpret_cast<const bf16x8*>(&h1[wr + l15][kb]);
#pragma unroll
        for (int n = 0; n < 7; ++n) {
            const bf16x8 bfr = *reinterpret_cast<const bf16x8*>(
                w2t + (size_t)(n * 16 + l15) * K2P + kb);
            acc2[n] = __builtin_amdgcn_mfma_f32_16x16x32_bf16(af, bfr, acc2[n], 0, 0, 0);
        }
    }

#pragma unroll
    for (int n = 0; n < 7; ++n) {
        const int c = n * 16 + l15;
        bias[n] = (c < 100) ? b2[c] : 0.f;
    }
#pragma unroll
    for (int n = 0; n < 7; ++n) {
        const int col = n * 16 + l15;
        if (col < 100)
#pragma unroll
            for (int q = 0; q < 4; ++q) {
                const float v = fmaxf(acc2[n][q] + bias[n], 0.f);
                h2[wr + lk * 4 + q][col] = f2bf(v);
            }
    }
    __builtin_amdgcn_sched_barrier(0);

    // ---- GEMM3: out = h2 @ W3 + b3
    f32x4 acc3 = (f32x4){0.f, 0.f, 0.f, 0.f};
#pragma unroll
    for (int ks = 0; ks < 4; ++ks) {
        const int kb = ks * 32 + lk * 8;
        const bf16x8 bfr = *reinterpret_cast<const bf16x8*>(
            w3t + (size_t)l15 * K2P + kb);
        const bf16x8 af = *reinterpret_cast<const bf16x8*>(&h2[wr + l15][kb]);
        acc3 = __builtin_amdgcn_mfma_f32_16x16x32_bf16(af, bfr, acc3, 0, 0, 0);
    }

    if (l15 < 10) {
        const float bb = b3[l15];
#pragma unroll
        for (int q = 0; q < 4; ++q) {
            const int row = b0 + wr + lk * 4 + q;
            out[(size_t)row * 10 + l15] = acc3[q] + bb;
        }
    }
}

extern "C" void kernel_launch(void* const* d_in, const int* in_sizes, int n_in,
                              void* d_out, int out_size, void* d_ws, size_t ws_size,
                              hipStream_t stream) {
    const float* x      = (const float*)d_in[0];
    const float* w_conv = (const float*)d_in[1];
    const float* W1     = (const float*)d_in[2];
    const float* b1     = (const float*)d_in[3];
    const float* W2     = (const float*)d_in[4];
    const float* b2     = (const float*)d_in[5];
    const float* W3     = (const float*)d_in[6];
    const float* b3     = (const float*)d_in[7];
    float* out = (float*)d_out;
    unsigned short* ws = (unsigned short*)d_ws;

    build_weights<<<(WS_USHORTS + 255) / 256, 256, 0, stream>>>(w_conv, W1, W2, W3, ws);
    fused<<<32768 / BM, NT, 0, stream>>>(x, ws, b1, b2, b3, out);
}

// Round 6
// 38.346 us; speedup vs baseline: 1.9779x; 1.9779x over previous
//
#include <hip/hip_runtime.h>

// R6: LDS-staged fused conv+MLP (R2 structure, fixed).
//   - B (Weff) staged in LDS per K-stage, shared by all 4 waves (4x less B traffic).
//   - x staged fp32 via global_load_lds width=16 (no dest regs -> nothing to
//     sink/spill; R5's spill disease impossible).
//   - 2-phase schedule: issue(t+1) -> compute(t) -> syncthreads; 2 blocks/CU
//     so drains overlap the other block's issues.
//   - XOR source-side swizzle on xs and bs (linear LDS dest + swizzled global
//     source + swizzled ds_read; same involution both sides).
//   - 12 LDS stages (k<768) + register tail stage (k 768..783).

typedef __attribute__((ext_vector_type(8))) short bf16x8;
typedef __attribute__((ext_vector_type(4))) float f32x4;

#define KP1 832     // Weff K padded (784 -> 13*64)
#define NP  112     // hidden N padded
#define K2P 128     // GEMM2/3 K padded
#define BM  64
#define NT  256

#define W2T_OFF (NP * KP1)              // 93184
#define W3T_OFF (W2T_OFF + NP * K2P)    // 107520
#define WS_USHORTS (W3T_OFF + 16 * K2P) // 109568

__device__ __forceinline__ unsigned short f2bf(float f) {
    unsigned int u = __float_as_uint(f);
    u += 0x7FFFu + ((u >> 16) & 1u);    // RNE
    return (unsigned short)(u >> 16);
}

__device__ __forceinline__ unsigned int pkbf(float a, float b) {
    unsigned int r;
    asm("v_cvt_pk_bf16_f32 %0, %1, %2" : "=v"(r) : "v"(a), "v"(b));
    return r;
}

__device__ __forceinline__ bf16x8 cvt8(float4 a, float4 b) {
    union { unsigned int w[4]; bf16x8 v; } u;
    u.w[0] = pkbf(a.x, a.y);
    u.w[1] = pkbf(a.z, a.w);
    u.w[2] = pkbf(b.x, b.y);
    u.w[3] = pkbf(b.z, b.w);
    return u.v;
}

__device__ __forceinline__ void gload_lds16(const void* g, void* l) {
    __builtin_amdgcn_global_load_lds(
        (const __attribute__((address_space(1))) unsigned int*)g,
        (__attribute__((address_space(3))) unsigned int*)l, 16, 0, 0);
}

// ---------------- Kernel A: all weights -> bf16, transposed, padded
__global__ void build_weights(const float* __restrict__ w_conv,
                              const float* __restrict__ W1,
                              const float* __restrict__ W2,
                              const float* __restrict__ W3,
                              unsigned short* __restrict__ ws) {
    const int idx = blockIdx.x * 256 + threadIdx.x;
    if (idx >= WS_USHORTS) return;
    float v = 0.f;
    if (idx < W2T_OFF) {                       // weff_t[col][p]
        const int col = idx / KP1, p = idx % KP1;
        if (col < 100 && p < 784) {
            const int y = p / 28, xx = p % 28;
#pragma unroll
            for (int ky = 0; ky < 3; ++ky) {
                const int py = y - ky;
                if (py < 0 || py >= 26) continue;
#pragma unroll
                for (int kx = 0; kx < 3; ++kx) {
                    const int px = xx - kx;
                    if (px < 0 || px >= 26) continue;
                    v += w_conv[ky * 3 + kx] * W1[(py * 26 + px) * 100 + col];
                }
            }
        }
    } else if (idx < W3T_OFF) {                // w2t[col][k]
        const int r = idx - W2T_OFF;
        const int col = r / K2P, k = r % K2P;
        if (col < 100 && k < 100) v = W2[k * 100 + col];
    } else {                                   // w3t[col][k]
        const int r = idx - W3T_OFF;
        const int col = r / K2P, k = r % K2P;
        if (col < 10 && k < 100) v = W3[k * 10 + col];
    }
    ws[idx] = f2bf(v);
}

// ---------------- Kernel B: fused
__global__ __launch_bounds__(NT, 2)
void fused(const float* __restrict__ x,
           const unsigned short* __restrict__ wst,
           const float* __restrict__ b1,
           const float* __restrict__ b2,
           const float* __restrict__ b3,
           float* __restrict__ out) {
    __shared__ __attribute__((aligned(16))) float          xs[2][64][64];   // 32768 B
    __shared__ __attribute__((aligned(16))) unsigned short bs[2][112][64];  // 28672 B
    __shared__ __attribute__((aligned(16))) unsigned short h1[64][136];     // 17408 B
    unsigned short (*h2)[136] = reinterpret_cast<unsigned short(*)[136]>(&xs[0][0][0]);

    const int tid  = threadIdx.x;
    const int lane = tid & 63;
    const int wv   = tid >> 6;       // wave owns rows wv*16 .. wv*16+15
    const int l15  = lane & 15;
    const int lk   = lane >> 4;      // 0..3
    const int b0   = blockIdx.x * BM;
    const int wr   = wv * 16;

    const unsigned short* weff = wst;
    const unsigned short* w2t  = wst + W2T_OFF;
    const unsigned short* w3t  = wst + W3T_OFF;

    // zero h1 k-pad (cols 100..127), own rows
    for (int f = lane; f < 16 * 14; f += 64) {
        const int r = wr + f / 14, c = 100 + (f % 14) * 2;
        *reinterpret_cast<unsigned int*>(&h1[r][c]) = 0u;
    }

    f32x4 acc[7];
#pragma unroll
    for (int n = 0; n < 7; ++n) acc[n] = (f32x4){0.f, 0.f, 0.f, 0.f};

    // ---- issue stage kt into buf: x (4 issues/wave) + B (3-4 issues/wave)
    auto issue = [&](int kt, int buf) {
#pragma unroll
        for (int q = 0; q < 4; ++q) {
            const int row = wr + q * 4 + (lane >> 4);
            const int col = ((lane & 15) ^ (row & 7)) * 4;      // inverse swizzle
            const float* g = x + (size_t)(b0 + row) * 784 + kt * 64 + col;
            gload_lds16(g, (void*)&xs[buf][wr + q * 4][0]);
        }
#pragma unroll
        for (int i = 0; i < 4; ++i) {
            const int j = wv + 4 * i;
            if (j < 14) {
                const int row = j * 8 + (lane >> 3);
                const int col = ((lane & 7) ^ (lane >> 3)) * 8; // inverse swizzle
                const unsigned short* g = weff + (size_t)row * KP1 + kt * 64 + col;
                gload_lds16(g, (void*)&bs[buf][j * 8][0]);
            }
        }
    };

    // ---- compute one 64-k stage from buf (swizzled reads)
    auto computeStage = [&](int buf) {
        const int arow = wr + l15;
        const int sA = (arow & 7) << 4;           // byte XOR within 256B row
        const int sB = (l15 & 7) << 4;            // byte XOR within 128B row
        const char* ap = (const char*)&xs[buf][arow][0];
#pragma unroll
        for (int ks = 0; ks < 2; ++ks) {
            const float4 lo = *reinterpret_cast<const float4*>(ap + ((ks * 128 + lk * 32 +  0) ^ sA));
            const float4 hi = *reinterpret_cast<const float4*>(ap + ((ks * 128 + lk * 32 + 16) ^ sA));
            const bf16x8 af = cvt8(lo, hi);
#pragma unroll
            for (int n = 0; n < 7; ++n) {
                const char* bp = (const char*)&bs[buf][n * 16 + l15][0];
                const bf16x8 bfr = *reinterpret_cast<const bf16x8*>(bp + ((ks * 64 + lk * 16) ^ sB));
                acc[n] = __builtin_amdgcn_mfma_f32_16x16x32_bf16(af, bfr, acc[n], 0, 0, 0);
            }
        }
    };

    // ---- GEMM1 main: 12 LDS stages (k 0..767), 2-phase double-buffer
    issue(0, 0);
    __syncthreads();
#pragma unroll 1
    for (int t = 0; t < 12; ++t) {
        if (t < 11) issue(t + 1, (t + 1) & 1);
        __builtin_amdgcn_sched_barrier(0);   // issues stay before compute
        computeStage(t & 1);
        __syncthreads();                     // drain + all waves done with buf
    }

    // ---- GEMM1 tail: k 768..783 direct from global (weff pad kills k>=784)
    {
        float4 t0 = (float4){0.f, 0.f, 0.f, 0.f}, t1 = t0;
        if (lk < 2) {
            const float* xp = x + (size_t)(b0 + wr + l15) * 784 + 768 + lk * 8;
            t0 = *reinterpret_cast<const float4*>(xp);
            t1 = *reinterpret_cast<const float4*>(xp + 4);
        }
        const bf16x8 aft = cvt8(t0, t1);
#pragma unroll
        for (int n = 0; n < 7; ++n) {
            const bf16x8 bft = *reinterpret_cast<const bf16x8*>(
                weff + (size_t)(n * 16 + l15) * KP1 + 768 + lk * 8);
            acc[n] = __builtin_amdgcn_mfma_f32_16x16x32_bf16(aft, bft, acc[n], 0, 0, 0);
        }
    }

    // ---- h1 = relu(acc + b1) -> LDS (own rows); zero h2 pad (h2 aliases xs)
    float bias[7];
#pragma unroll
    for (int n = 0; n < 7; ++n) {
        const int c = n * 16 + l15;
        bias[n] = (c < 100) ? b1[c] : 0.f;
    }
#pragma unroll
    for (int n = 0; n < 7; ++n) {
        const int col = n * 16 + l15;
        if (col < 100)
#pragma unroll
            for (int q = 0; q < 4; ++q) {
                const float v = fmaxf(acc[n][q] + bias[n], 0.f);
                h1[wr + lk * 4 + q][col] = f2bf(v);
            }
    }
    for (int f = lane; f < 16 * 14; f += 64) {      // h2 k-pad zero (own rows)
        const int r = wr + f / 14, c = 100 + (f % 14) * 2;
        *reinterpret_cast<unsigned int*>(&h2[r][c]) = 0u;
    }
    __builtin_amdgcn_sched_barrier(0);

    // ---- GEMM2: h2 = relu(h1 @ W2 + b2), B direct from global (L2)
    f32x4 acc2[7];
#pragma unroll
    for (int n = 0; n < 7; ++n) acc2[n] = (f32x4){0.f, 0.f, 0.f, 0.f};
#pragma unroll
    for (int ks = 0; ks < 4; ++ks) {
        const int kb = ks * 32 + lk * 8;
        const bf16x8 af = *reinterpret_cast<const bf16x8*>(&h1[wr + l15][kb]);
#pragma unroll
        for (int n = 0; n < 7; ++n) {
            const bf16x8 bfr = *reinterpret_cast<const bf16x8*>(
                w2t + (size_t)(n * 16 + l15) * K2P + kb);
            acc2[n] = __builtin_amdgcn_mfma_f32_16x16x32_bf16(af, bfr, acc2[n], 0, 0, 0);
        }
    }

#pragma unroll
    for (int n = 0; n < 7; ++n) {
        const int c = n * 16 + l15;
        bias[n] = (c < 100) ? b2[c] : 0.f;
    }
#pragma unroll
    for (int n = 0; n < 7; ++n) {
        const int col = n * 16 + l15;
        if (col < 100)
#pragma unroll
            for (int q = 0; q < 4; ++q) {
                const float v = fmaxf(acc2[n][q] + bias[n], 0.f);
                h2[wr + lk * 4 + q][col] = f2bf(v);
            }
    }
    __builtin_amdgcn_sched_barrier(0);

    // ---- GEMM3: out = h2 @ W3 + b3
    f32x4 acc3 = (f32x4){0.f, 0.f, 0.f, 0.f};
#pragma unroll
    for (int ks = 0; ks < 4; ++ks) {
        const int kb = ks * 32 + lk * 8;
        const bf16x8 bfr = *reinterpret_cast<const bf16x8*>(
            w3t + (size_t)l15 * K2P + kb);
        const bf16x8 af = *reinterpret_cast<const bf16x8*>(&h2[wr + l15][kb]);
        acc3 = __builtin_amdgcn_mfma_f32_16x16x32_bf16(af, bfr, acc3, 0, 0, 0);
    }

    if (l15 < 10) {
        const float bb = b3[l15];
#pragma unroll
        for (int q = 0; q < 4; ++q) {
            const int row = b0 + wr + lk * 4 + q;
            out[(size_t)row * 10 + l15] = acc3[q] + bb;
        }
    }
}

extern "C" void kernel_launch(void* const* d_in, const int* in_sizes, int n_in,
                              void* d_out, int out_size, void* d_ws, size_t ws_size,
                              hipStream_t stream) {
    const float* x      = (const float*)d_in[0];
    const float* w_conv = (const float*)d_in[1];
    const float* W1     = (const float*)d_in[2];
    const float* b1     = (const float*)d_in[3];
    const float* W2     = (const float*)d_in[4];
    const float* b2     = (const float*)d_in[5];
    const float* W3     = (const float*)d_in[6];
    const float* b3     = (const float*)d_in[7];
    float* out = (float*)d_out;
    unsigned short* ws = (unsigned short*)d_ws;

    build_weights<<<(WS_USHORTS + 255) / 256, 256, 0, stream>>>(w_conv, W1, W2, W3, ws);
    fused<<<32768 / BM, NT, 0, stream>>>(x, ws, b1, b2, b3, out);
}